// Round 6
// baseline (2133.183 us; speedup 1.0000x reference)
//
#include <hip/hip_runtime.h>

// ChemResBlock: S=16, A=512, F=64, L=12, 3 layers x 2 convs (shared weights/layer).
// Re-associated: yT[s][o][l*512+k] = sum_f x[s,k,f] w[o,l,f]   (l-major kl order)
//   out[s,a,o] = sum_{kl} connB[s,a,kl] * yT[s][o][kl] + bondW (+node), relu
// R6: ONE persistent kernel (512 blocks x 512 thr, 2/CU guaranteed) with
// flag-array global barriers; conn transpose-cast fused as phase 0.

typedef __attribute__((ext_vector_type(8))) short bf16x8;
typedef __attribute__((ext_vector_type(4))) float f32x4;
typedef unsigned short u16;
typedef unsigned int u32;

__device__ __forceinline__ u16 f2bf(float f) {
  union { float f; u32 u; } x; x.f = f;
  u32 r = x.u + 0x7fffu + ((x.u >> 16) & 1u);   // RNE
  return (u16)(r >> 16);
}

__device__ __forceinline__ void gload16(const void* g, void* l) {
  __builtin_amdgcn_global_load_lds((const __attribute__((address_space(1))) u32*)g,
                                   (__attribute__((address_space(3))) u32*)l, 16, 0, 0);
}

// ---------- prep ----------

// filters (3,64,12,66) -> wA [i][(l*64+o)][f] bf16 (drop bond cols)
__global__ __launch_bounds__(256) void k_w_pack(const float* __restrict__ filters,
                                                u16* __restrict__ wA) {
  int tid = blockIdx.x * 256 + threadIdx.x;  // < 3*768*64 = 147456
  int i = tid / 49152;
  int rem = tid - i * 49152;
  int row = rem >> 6, f = rem & 63;          // row = l*64+o
  int l = row >> 6, o = row & 63;
  wA[tid] = f2bf(filters[((size_t)((i * 64 + o) * 12 + l)) * 66 + f]);
}

// bondW[i][(s*512+a)*64+o] = sum_{l,j} bond[s,a,l,j] * filters[i,o,l,64+j]
__global__ __launch_bounds__(192) void k_bondw(const float* __restrict__ bond,
                                               const float* __restrict__ filters,
                                               float* __restrict__ bondW) {
  int blk = blockIdx.x;                      // s*512 + a
  int t = threadIdx.x;                       // 192 = 3 filters x 64 o
  __shared__ float lb[24];
  if (t < 24) lb[t] = bond[(size_t)blk * 24 + t];
  __syncthreads();
  int i = t >> 6, o = t & 63;
  float acc = 0.f;
#pragma unroll
  for (int l = 0; l < 12; ++l) {
    const float* wr = filters + ((size_t)((i * 64 + o) * 12 + l)) * 66 + 64;
    acc += lb[l * 2 + 0] * wr[0] + lb[l * 2 + 1] * wr[1];
  }
  bondW[(size_t)i * 524288 + (size_t)blk * 64 + o] = acc;
}

__global__ __launch_bounds__(256) void k_zero(u32* __restrict__ p, int n) {
  int i = blockIdx.x * 256 + threadIdx.x;
  if (i < n) p[i] = 0u;
}

// ---------- global barrier (512 blocks, all guaranteed resident) ----------
__device__ __forceinline__ void gbar(u32* bar, int phase, int bid, int tid) {
  __syncthreads();
  __threadfence();                                   // flush this block's writes
  u32* flags = bar + phase * 512;
  u32* go = bar + 6144;
  if (tid == 0)
    __hip_atomic_store(&flags[bid], 1u, __ATOMIC_RELAXED, __HIP_MEMORY_SCOPE_AGENT);
  if (bid == 0) {
    while (__hip_atomic_load(&flags[tid], __ATOMIC_RELAXED, __HIP_MEMORY_SCOPE_AGENT) == 0u)
      __builtin_amdgcn_s_sleep(1);
    __syncthreads();
    if (tid == 0) {
      __threadfence();
      __hip_atomic_store(go, (u32)(phase + 1), __ATOMIC_RELAXED, __HIP_MEMORY_SCOPE_AGENT);
    }
  }
  if (tid == 0) {
    while (__hip_atomic_load(go, __ATOMIC_RELAXED, __HIP_MEMORY_SCOPE_AGENT) < (u32)(phase + 1))
      __builtin_amdgcn_s_sleep(1);
  }
  __syncthreads();
  __threadfence();                                   // invalidate stale caches
}

// ---------- stage B tile: 64x64, BK=64, 12 steps, dbuf ----------
__device__ __forceinline__ void stageB_tile(unsigned char* shm, int tile, int tid,
                                            const u16* __restrict__ connB,
                                            const u16* __restrict__ yTb,
                                            float* __restrict__ pOut) {
  const int xcd = tile & 7, rest = tile >> 3;
  const int s = xcd * 2 + (rest & 1);
  const int rest2 = rest >> 1;
  const int bx = rest2 & 7, kq = rest2 >> 3;
  const int row0 = bx * 64;
  const int k0 = kq * 768;
  const u16* Ab = connB + (size_t)s * 3145728 + (size_t)row0 * 6144 + k0;
  const u16* Bb = yTb + (size_t)s * 393216 + k0;
  u16* lA0 = (u16*)shm;
  u16* lA1 = lA0 + 4096;
  u16* lB0 = lA0 + 8192;
  u16* lB1 = lA0 + 12288;
  const int lane = tid & 63, wid = tid >> 6;
  const int r = lane & 15, g = lane >> 4;
  const int wr = wid & 3, wc = wid >> 2;
  const int isA = wid < 4;
  const int wseg = (isA ? wid : wid - 4) * 16;
  const u16* sbase = isA ? Ab : Bb;
  const int lrow = lane >> 3;
  const int lslot = lane & 7;
  f32x4 acc[2] = {};

#define STAGEX(ST, LA, LB)                                                       \
  {                                                                              \
    u16* lds = isA ? (LA) : (LB);                                                \
    _Pragma("unroll")                                                            \
    for (int h = 0; h < 2; ++h) {                                                \
      const int R0 = wseg + h * 8;                                               \
      const int row = R0 + lrow;                                                 \
      const int slot = lslot ^ (row & 7);                                        \
      gload16(sbase + (size_t)row * 6144 + (ST) * 64 + slot * 8, lds + R0 * 64); \
    }                                                                            \
  }
#define COMPX(LA, LB)                                                            \
  {                                                                              \
    const int arow = wr * 16 + r;                                                \
    _Pragma("unroll")                                                            \
    for (int ks = 0; ks < 2; ++ks) {                                             \
      bf16x8 av = *(const bf16x8*)&(LA)[arow * 64 + ((((ks << 2) + g) ^ (arow & 7)) << 3)]; \
      _Pragma("unroll")                                                          \
      for (int c = 0; c < 2; ++c) {                                              \
        const int col = wc * 32 + c * 16 + r;                                    \
        bf16x8 bv = *(const bf16x8*)&(LB)[col * 64 + ((((ks << 2) + g) ^ (col & 7)) << 3)]; \
        acc[c] = __builtin_amdgcn_mfma_f32_16x16x32_bf16(av, bv, acc[c], 0, 0, 0); \
      }                                                                          \
    }                                                                            \
  }

  STAGEX(0, lA0, lB0);
  __syncthreads();
#pragma unroll
  for (int st = 0; st < 12; st += 2) {
    if (st + 1 < 12) STAGEX(st + 1, lA1, lB1);
    COMPX(lA0, lB0);
    __syncthreads();
    if (st + 2 < 12) STAGEX(st + 2, lA0, lB0);
    COMPX(lA1, lB1);
    __syncthreads();
  }
#undef STAGEX
#undef COMPX
  float* po = pOut + (size_t)kq * 524288 + ((size_t)s * 512 + row0) * 64;
#pragma unroll
  for (int c = 0; c < 2; ++c)
#pragma unroll
    for (int r2 = 0; r2 < 4; ++r2) {
      int m = wr * 16 + g * 4 + r2;
      int o = wc * 32 + c * 16 + r;
      po[m * 64 + o] = acc[c][r2];
    }
}

// ---------- yT phase: x (node or reduce+epilogue) -> yT[s][o][l*512+k] ----------
// active blocks 0..127: s = bid>>3, k0 = (bid&7)*64. mode 0: x=node; 1: mid; 2: final->outF.
__device__ __forceinline__ void yT_phase(unsigned char* shm, int bid, int tid,
                                         const float* __restrict__ node,
                                         const float* __restrict__ pOut,
                                         const float* __restrict__ bias,
                                         const u16* __restrict__ wAf,
                                         u16* __restrict__ yT,
                                         float* __restrict__ outF,
                                         int mode, int addNode) {
  const int s = bid >> 3, k0 = (bid & 7) * 64;
  const int lane = tid & 63, wid = tid >> 6;
  const int r = lane & 15, g = lane >> 4;
  u16* xs = (u16*)shm;                           // [64][64] bf16, slot-swizzled
  u16* tr = (u16*)(shm + 8192) + wid * (16 * 72);  // per-wave 16x72

  {
    const int row = tid >> 3, f0 = (tid & 7) * 8;
    const size_t e = ((size_t)(s * 512) + k0 + row) * 64 + f0;
    float v[8];
    if (mode == 0) {
      float4 a = *(const float4*)&node[e], b = *(const float4*)&node[e + 4];
      v[0] = a.x; v[1] = a.y; v[2] = a.z; v[3] = a.w;
      v[4] = b.x; v[5] = b.y; v[6] = b.z; v[7] = b.w;
    } else {
      float4 sa = {0, 0, 0, 0}, sb = {0, 0, 0, 0};
#pragma unroll
      for (int q = 0; q < 8; ++q) {
        float4 a = *(const float4*)&pOut[(size_t)q * 524288 + e];
        float4 b = *(const float4*)&pOut[(size_t)q * 524288 + e + 4];
        sa.x += a.x; sa.y += a.y; sa.z += a.z; sa.w += a.w;
        sb.x += b.x; sb.y += b.y; sb.z += b.z; sb.w += b.w;
      }
      float4 ba = *(const float4*)&bias[e], bb = *(const float4*)&bias[e + 4];
      sa.x += ba.x; sa.y += ba.y; sa.z += ba.z; sa.w += ba.w;
      sb.x += bb.x; sb.y += bb.y; sb.z += bb.z; sb.w += bb.w;
      if (addNode) {
        float4 na = *(const float4*)&node[e], nb = *(const float4*)&node[e + 4];
        sa.x += na.x; sa.y += na.y; sa.z += na.z; sa.w += na.w;
        sb.x += nb.x; sb.y += nb.y; sb.z += nb.z; sb.w += nb.w;
      }
      v[0] = fmaxf(sa.x, 0.f); v[1] = fmaxf(sa.y, 0.f);
      v[2] = fmaxf(sa.z, 0.f); v[3] = fmaxf(sa.w, 0.f);
      v[4] = fmaxf(sb.x, 0.f); v[5] = fmaxf(sb.y, 0.f);
      v[6] = fmaxf(sb.z, 0.f); v[7] = fmaxf(sb.w, 0.f);
      if (mode == 2) {                          // final conv: write f32 d_out
        float4 o0, o1;
        o0.x = v[0]; o0.y = v[1]; o0.z = v[2]; o0.w = v[3];
        o1.x = v[4]; o1.y = v[5]; o1.z = v[6]; o1.w = v[7];
        *(float4*)&outF[e] = o0;
        *(float4*)&outF[e + 4] = o1;
        return;                                 // uniform across block
      }
    }
    ushort4 h0, h1;
    h0.x = f2bf(v[0]); h0.y = f2bf(v[1]); h0.z = f2bf(v[2]); h0.w = f2bf(v[3]);
    h1.x = f2bf(v[4]); h1.y = f2bf(v[5]); h1.z = f2bf(v[6]); h1.w = f2bf(v[7]);
    const int slot = (f0 >> 3) ^ (row & 7);
    *(ushort4*)&xs[row * 64 + slot * 8] = h0;
    *(ushort4*)&xs[row * 64 + slot * 8 + 4] = h1;
  }
  __syncthreads();

  // 48 units (12 l x 4 ot) over 8 waves: wave wid does u = wid*6 .. wid*6+5
#pragma unroll
  for (int i = 0; i < 6; ++i) {
    const int u = wid * 6 + i, l = u >> 2, ot = u & 3;
    f32x4 acc[4] = {};                          // kt = 0..3 (D [16 o][64 k])
#pragma unroll
    for (int ks = 0; ks < 2; ++ks) {
      bf16x8 av = *(const bf16x8*)&wAf[(size_t)(l * 64 + ot * 16 + r) * 64 + ks * 32 + g * 8];
#pragma unroll
      for (int kt = 0; kt < 4; ++kt) {
        const int kk = kt * 16 + r;
        bf16x8 bv = *(const bf16x8*)&xs[kk * 64 + (((ks * 4 + g) ^ (kk & 7)) << 3)];
        acc[kt] = __builtin_amdgcn_mfma_f32_16x16x32_bf16(av, bv, acc[kt], 0, 0, 0);
      }
    }
    // transpose via per-wave LDS: tr[o_local][k]
#pragma unroll
    for (int kt = 0; kt < 4; ++kt)
#pragma unroll
      for (int r2 = 0; r2 < 4; ++r2)
        tr[(g * 4 + r2) * 72 + kt * 16 + r] = f2bf(acc[kt][r2]);
    const int orow = lane >> 2, part = lane & 3;
    bf16x8 vv0 = *(const bf16x8*)&tr[orow * 72 + part * 16];
    bf16x8 vv1 = *(const bf16x8*)&tr[orow * 72 + part * 16 + 8];
    u16* yb = yT + ((size_t)(s * 64) + ot * 16 + orow) * 6144 + l * 512 + k0 + part * 16;
    *(bf16x8*)yb = vv0;
    *(bf16x8*)(yb + 8) = vv1;
  }
}

// ---------- the persistent mega-kernel ----------
__global__ __launch_bounds__(512, 4) void k_mega(const float* __restrict__ node,
                                                 const float* __restrict__ conn,
                                                 const u16* __restrict__ wA,
                                                 const float* __restrict__ bW,
                                                 u16* __restrict__ connB,
                                                 u16* __restrict__ yT,
                                                 float* __restrict__ pOut,
                                                 float* __restrict__ outF,
                                                 u32* __restrict__ bar) {
  __shared__ __align__(16) unsigned char shm[32768];
  const int bid = blockIdx.x, tid = threadIdx.x;

  // ---- P0: conn (s,a,k,l) f32 -> connB [s*512+a][l*512+k] bf16 (16 tiles/block)
  {
    float* tf = (float*)shm;                   // [512 k][13] padded
    for (int t = 0; t < 16; ++t) {
      const int sa = bid * 16 + t;
      const float4* src = (const float4*)(conn + (size_t)sa * 6144);
#pragma unroll
      for (int i = 0; i < 3; ++i) {
        float4 v = src[i * 512 + tid];
        const int e = (i * 512 + tid) * 4;
        { int ee = e + 0; int k = (int)(((u32)ee * 43691u) >> 19); tf[k * 13 + (ee - k * 12)] = v.x; }
        { int ee = e + 1; int k = (int)(((u32)ee * 43691u) >> 19); tf[k * 13 + (ee - k * 12)] = v.y; }
        { int ee = e + 2; int k = (int)(((u32)ee * 43691u) >> 19); tf[k * 13 + (ee - k * 12)] = v.z; }
        { int ee = e + 3; int k = (int)(((u32)ee * 43691u) >> 19); tf[k * 13 + (ee - k * 12)] = v.w; }
      }
      __syncthreads();
      u16* dst = connB + (size_t)sa * 6144;
#pragma unroll
      for (int i = 0; i < 3; ++i) {
        const int m = tid * 12 + i * 4;        // m = l*512 + k target order
        ushort4 w;
        { int mm = m + 0; w.x = f2bf(tf[(mm & 511) * 13 + (mm >> 9)]); }
        { int mm = m + 1; w.y = f2bf(tf[(mm & 511) * 13 + (mm >> 9)]); }
        { int mm = m + 2; w.z = f2bf(tf[(mm & 511) * 13 + (mm >> 9)]); }
        { int mm = m + 3; w.w = f2bf(tf[(mm & 511) * 13 + (mm >> 9)]); }
        *(ushort4*)&dst[m] = w;
      }
      __syncthreads();
    }
  }

  // ---- P1: initial yT from node (filter 0)
  if (bid < 128) yT_phase(shm, bid, tid, node, pOut, bW, wA, yT, outF, 0, 0);

  // ---- conv loop: 6 convs, 2 barriers each
  for (int j = 0; j < 6; ++j) {
    gbar(bar, 2 * j, bid, tid);                // connB+yT ready
    stageB_tile(shm, bid, tid, connB, yT, pOut);
    __syncthreads();
    stageB_tile(shm, bid + 512, tid, connB, yT, pOut);
    gbar(bar, 2 * j + 1, bid, tid);            // pOut ready
    if (j < 5) {
      if (bid < 128)
        yT_phase(shm, bid, tid, node, pOut, bW + (size_t)(j >> 1) * 524288,
                 wA + (size_t)((j + 1) >> 1) * 49152, yT, outF, 1, j & 1);
    } else {
      if (bid < 128)
        yT_phase(shm, bid, tid, node, pOut, bW + (size_t)2 * 524288,
                 wA, yT, outF, 2, 1);
    }
  }
}

// ---------- fallback (f32, correct, slow) if ws too small ----------
__global__ __launch_bounds__(256) void k_fb_conv(const float* __restrict__ x,
                                                 const float* __restrict__ conn,
                                                 const float* __restrict__ bond,
                                                 const float* __restrict__ filt,
                                                 const float* __restrict__ node,
                                                 float* __restrict__ out, int addNode) {
  const int s = blockIdx.y, a = blockIdx.x;
  const int t = threadIdx.x;
  const int f = t & 63, lg = t >> 6;
  __shared__ float ncv[12 * 64];
  __shared__ float red[4][64];
  const float* cb = conn + ((size_t)(s * 512 + a)) * 6144;
  const float* xb = x + (size_t)s * 32768;
  float a0 = 0.f, a1 = 0.f, a2 = 0.f;
  for (int k = 0; k < 512; ++k) {
    float xv = xb[k * 64 + f];
    const float* cr = cb + k * 12 + lg * 3;
    a0 += cr[0] * xv; a1 += cr[1] * xv; a2 += cr[2] * xv;
  }
  ncv[(lg * 3 + 0) * 64 + f] = a0;
  ncv[(lg * 3 + 1) * 64 + f] = a1;
  ncv[(lg * 3 + 2) * 64 + f] = a2;
  __syncthreads();
  float p = 0.f;
  for (int l = lg * 3; l < lg * 3 + 3; ++l) {
    const float* wr = filt + ((size_t)(f * 12 + l)) * 66;
    float q = 0.f;
    for (int f2 = 0; f2 < 64; ++f2) q += ncv[l * 64 + f2] * wr[f2];
    q += bond[((size_t)(s * 512 + a) * 12 + l) * 2 + 0] * wr[64];
    q += bond[((size_t)(s * 512 + a) * 12 + l) * 2 + 1] * wr[65];
    p += q;
  }
  red[lg][f] = p;
  __syncthreads();
  if (t < 64) {
    float v = red[0][t] + red[1][t] + red[2][t] + red[3][t];
    if (addNode) v += node[((size_t)(s * 512 + a)) * 64 + t];
    out[((size_t)(s * 512 + a)) * 64 + t] = fmaxf(v, 0.f);
  }
}

extern "C" void kernel_launch(void* const* d_in, const int* in_sizes, int n_in,
                              void* d_out, int out_size, void* d_ws, size_t ws_size,
                              hipStream_t stream) {
  (void)in_sizes; (void)n_in; (void)out_size;
  const float* node    = (const float*)d_in[0];
  const float* conn    = (const float*)d_in[1];
  const float* bond    = (const float*)d_in[2];
  const float* filters = (const float*)d_in[3];
  float* outF = (float*)d_out;

  const size_t OFF_CONNB = 0;           // 16*512*6144*2 = 100,663,296
  const size_t OFF_YT    = 100663296;   // 16*64*6144*2  =  12,582,912
  const size_t OFF_WA    = 113246208;   // 3*768*64*2    =     294,912
  const size_t OFF_BW    = 113541120;   // 3*16*512*64*4 =   6,291,456
  const size_t OFF_POUT  = 119832576;   // 8*16*512*64*4 =  16,777,216
  const size_t OFF_BAR   = 136609792;   // 12*512+1 u32  =      24,580
  const size_t WS_NEED   = 136634880;

  if (ws_size >= WS_NEED) {
    unsigned char* ws = (unsigned char*)d_ws;
    u16* connB = (u16*)(ws + OFF_CONNB);
    u16* yT    = (u16*)(ws + OFF_YT);
    u16* wA    = (u16*)(ws + OFF_WA);
    float* bW  = (float*)(ws + OFF_BW);
    float* pO  = (float*)(ws + OFF_POUT);
    u32* bar   = (u32*)(ws + OFF_BAR);

    k_w_pack<<<dim3(576), dim3(256), 0, stream>>>(filters, wA);
    k_bondw<<<dim3(8192), dim3(192), 0, stream>>>(bond, filters, bW);
    k_zero<<<dim3(25), dim3(256), 0, stream>>>(bar, 6145);
    k_mega<<<dim3(512), dim3(512), 0, stream>>>(node, conn, wA, bW,
                                                connB, yT, pO, outF, bar);
  } else {
    float* buf = (float*)d_ws;
    const float* xc = node;
    for (int j = 0; j < 6; ++j) {
      int i = j >> 1;
      float* dst = (j & 1) ? outF : buf;
      k_fb_conv<<<dim3(512, 16), dim3(256), 0, stream>>>(xc, conn, bond,
                                                         filters + (size_t)i * 50688,
                                                         node, dst, j & 1);
      xc = dst;
    }
  }
}

// Round 7
// 242.492 us; speedup vs baseline: 8.7969x; 8.7969x over previous
//
#include <hip/hip_runtime.h>

// ChemResBlock: S=16, A=512, F=64, L=12, 3 layers x 2 convs (shared weights/layer).
// Re-associated: yT[s][o][l*512+k] = sum_f x[s,k,f] w[o,l,f]   (l-major kl)
//   out[s,a,o] = sum_{kl} connB[s,a,kl] * yT[s][o][kl] + bondW (+node), relu
// R7: multi-kernel (R5 skeleton revert); stageB with counted-vmcnt 3-buffer
// pipeline (no vmcnt(0) drain in loop); prep kernels merged; bondw restructured.

typedef __attribute__((ext_vector_type(8))) short bf16x8;
typedef __attribute__((ext_vector_type(4))) float f32x4;
typedef unsigned short u16;
typedef unsigned int u32;

__device__ __forceinline__ u16 f2bf(float f) {
  union { float f; u32 u; } x; x.f = f;
  u32 r = x.u + 0x7fffu + ((x.u >> 16) & 1u);   // RNE
  return (u16)(r >> 16);
}

__device__ __forceinline__ void gload16(const void* g, void* l) {
  __builtin_amdgcn_global_load_lds((const __attribute__((address_space(1))) u32*)g,
                                   (__attribute__((address_space(3))) u32*)l, 16, 0, 0);
}

// ---------- k_prep: [0,2048) conn cast | [2048,2624) w_pack | [2624,3136) bondw ----------
__global__ __launch_bounds__(256) void k_prep(const float* __restrict__ conn,
                                              const float* __restrict__ filters,
                                              const float* __restrict__ bond,
                                              u16* __restrict__ connB,
                                              u16* __restrict__ wA,
                                              float* __restrict__ bW) {
  const int bid = blockIdx.x, tid = threadIdx.x;
  if (bid < 2048) {
    // conn f32 -> connB bf16 (elementwise, natural layout = GEMM A layout, kl k-major)
    const unsigned n8 = 6291456u, stride = 2048 * 256;
    for (unsigned j = bid * 256 + tid; j < n8; j += stride) {
      const float4* s4 = (const float4*)conn;
      float4 a = s4[2 * (size_t)j], b = s4[2 * (size_t)j + 1];
      ushort4 lo, hi;
      lo.x = f2bf(a.x); lo.y = f2bf(a.y); lo.z = f2bf(a.z); lo.w = f2bf(a.w);
      hi.x = f2bf(b.x); hi.y = f2bf(b.y); hi.z = f2bf(b.z); hi.w = f2bf(b.w);
      ((ushort4*)connB)[2 * (size_t)j] = lo;
      ((ushort4*)connB)[2 * (size_t)j + 1] = hi;
    }
  } else if (bid < 2624) {
    // filters (3,64,12,66) -> wA [i][(l*64+o)][f] bf16
    int t = (bid - 2048) * 256 + tid;        // < 147456
    int i = t / 49152;
    int rem = t - i * 49152;
    int row = rem >> 6, f = rem & 63;
    int l = row >> 6, o = row & 63;
    wA[t] = f2bf(filters[((size_t)((i * 64 + o) * 12 + l)) * 66 + f]);
  } else {
    // bondW[i][(sa)*64+o] = sum_{l,j} bond[sa,l,j] * filters[i,o,l,64+j]
    __shared__ float wb[4608];               // [i][o][l*2+j]
    __shared__ float lb[16 * 24];
    const int sa0 = (bid - 2624) * 16;
    for (int idx = tid; idx < 4608; idx += 256) {
      int i = idx / 1536, rem = idx - i * 1536;
      int o = rem / 24, lj = rem - o * 24;
      wb[idx] = filters[((size_t)((i * 64 + o) * 12 + (lj >> 1))) * 66 + 64 + (lj & 1)];
    }
    for (int t = tid; t < 384; t += 256)
      lb[t] = bond[(size_t)sa0 * 24 + t];
    __syncthreads();
#pragma unroll
    for (int it = 0; it < 12; ++it) {
      int idx = it * 256 + tid;              // < 3072 = 16sa x 3i x 64o
      int sl = idx / 192, rem = idx - sl * 192;
      int i = rem >> 6, o = rem & 63;
      float acc = 0.f;
#pragma unroll
      for (int lj = 0; lj < 24; ++lj)
        acc += lb[sl * 24 + lj] * wb[i * 1536 + o * 24 + lj];
      bW[(size_t)i * 524288 + (size_t)(sa0 + sl) * 64 + o] = acc;
    }
  }
}

// ---------- k_yT: x (node | reduce+epilogue) -> yT[s][o][l*512+k] ----------
// grid 128 (8 ktiles x 16 s), 512 thr. mode 0: x=node; 1: mid conv; 2: final->outF.
__global__ __launch_bounds__(512) void k_yT(const float* __restrict__ node,
                                            const float* __restrict__ pOut,
                                            const float* __restrict__ bias,
                                            const u16* __restrict__ wAf,
                                            u16* __restrict__ yT,
                                            float* __restrict__ outF,
                                            int mode, int addNode) {
  const int bid = blockIdx.x, tid = threadIdx.x;
  const int s = bid >> 3, k0 = (bid & 7) * 64;
  const int lane = tid & 63, wid = tid >> 6;
  const int r = lane & 15, g = lane >> 4;
  __shared__ u16 xs[64 * 64];                // bf16 x tile, 16B-slot XOR (row&7)
  __shared__ u16 trs[8][16 * 72];
  u16* tr = trs[wid];

  {
    const int row = tid >> 3, f0 = (tid & 7) * 8;
    const size_t e = ((size_t)(s * 512) + k0 + row) * 64 + f0;
    float v[8];
    if (mode == 0) {
      float4 a = *(const float4*)&node[e], b = *(const float4*)&node[e + 4];
      v[0] = a.x; v[1] = a.y; v[2] = a.z; v[3] = a.w;
      v[4] = b.x; v[5] = b.y; v[6] = b.z; v[7] = b.w;
    } else {
      float4 sa = {0, 0, 0, 0}, sb = {0, 0, 0, 0};
#pragma unroll
      for (int q = 0; q < 4; ++q) {
        float4 a = *(const float4*)&pOut[(size_t)q * 524288 + e];
        float4 b = *(const float4*)&pOut[(size_t)q * 524288 + e + 4];
        sa.x += a.x; sa.y += a.y; sa.z += a.z; sa.w += a.w;
        sb.x += b.x; sb.y += b.y; sb.z += b.z; sb.w += b.w;
      }
      float4 ba = *(const float4*)&bias[e], bb = *(const float4*)&bias[e + 4];
      sa.x += ba.x; sa.y += ba.y; sa.z += ba.z; sa.w += ba.w;
      sb.x += bb.x; sb.y += bb.y; sb.z += bb.z; sb.w += bb.w;
      if (addNode) {
        float4 na = *(const float4*)&node[e], nb = *(const float4*)&node[e + 4];
        sa.x += na.x; sa.y += na.y; sa.z += na.z; sa.w += na.w;
        sb.x += nb.x; sb.y += nb.y; sb.z += nb.z; sb.w += nb.w;
      }
      v[0] = fmaxf(sa.x, 0.f); v[1] = fmaxf(sa.y, 0.f);
      v[2] = fmaxf(sa.z, 0.f); v[3] = fmaxf(sa.w, 0.f);
      v[4] = fmaxf(sb.x, 0.f); v[5] = fmaxf(sb.y, 0.f);
      v[6] = fmaxf(sb.z, 0.f); v[7] = fmaxf(sb.w, 0.f);
      if (mode == 2) {                       // final conv: f32 d_out, done
        float4 o0, o1;
        o0.x = v[0]; o0.y = v[1]; o0.z = v[2]; o0.w = v[3];
        o1.x = v[4]; o1.y = v[5]; o1.z = v[6]; o1.w = v[7];
        *(float4*)&outF[e] = o0;
        *(float4*)&outF[e + 4] = o1;
        return;
      }
    }
    ushort4 h0, h1;
    h0.x = f2bf(v[0]); h0.y = f2bf(v[1]); h0.z = f2bf(v[2]); h0.w = f2bf(v[3]);
    h1.x = f2bf(v[4]); h1.y = f2bf(v[5]); h1.z = f2bf(v[6]); h1.w = f2bf(v[7]);
    const int slot = (f0 >> 3) ^ (row & 7);
    *(ushort4*)&xs[row * 64 + slot * 8] = h0;
    *(ushort4*)&xs[row * 64 + slot * 8 + 4] = h1;
  }
  __syncthreads();

  // 48 units (12 l x 4 ot) over 8 waves
#pragma unroll
  for (int i = 0; i < 6; ++i) {
    const int u = wid * 6 + i, l = u >> 2, ot = u & 3;
    f32x4 acc[4] = {};                       // D [16 o][64 k]
#pragma unroll
    for (int ks = 0; ks < 2; ++ks) {
      bf16x8 av = *(const bf16x8*)&wAf[(size_t)(l * 64 + ot * 16 + r) * 64 + ks * 32 + g * 8];
#pragma unroll
      for (int kt = 0; kt < 4; ++kt) {
        const int kk = kt * 16 + r;
        bf16x8 bv = *(const bf16x8*)&xs[kk * 64 + (((ks * 4 + g) ^ (kk & 7)) << 3)];
        acc[kt] = __builtin_amdgcn_mfma_f32_16x16x32_bf16(av, bv, acc[kt], 0, 0, 0);
      }
    }
#pragma unroll
    for (int kt = 0; kt < 4; ++kt)
#pragma unroll
      for (int r2 = 0; r2 < 4; ++r2)
        tr[(g * 4 + r2) * 72 + kt * 16 + r] = f2bf(acc[kt][r2]);
    const int orow = lane >> 2, part = lane & 3;
    bf16x8 vv0 = *(const bf16x8*)&tr[orow * 72 + part * 16];
    bf16x8 vv1 = *(const bf16x8*)&tr[orow * 72 + part * 16 + 8];
    u16* yb = yT + ((size_t)(s * 64) + ot * 16 + orow) * 6144 + l * 512 + k0 + part * 16;
    *(bf16x8*)yb = vv0;
    *(bf16x8*)(yb + 8) = vv1;
  }
}

// ---------- stage B: counted-vmcnt 3-buffer pipeline ----------
// grid 512 (8 xcd x 2 s x 8 mtile x 4 kq), 64x64 tile, BK=64, 24 steps.
__global__ __launch_bounds__(512, 2) void k_stageB(const u16* __restrict__ connB,
                                                   const u16* __restrict__ yT,
                                                   float* __restrict__ pOut) {
  const int b = blockIdx.x;
  const int xcd = b & 7;
  const int s = xcd * 2 + ((b >> 3) & 1);
  const int bx = (b >> 4) & 7, kq = b >> 7;
  const int row0 = bx * 64, k0 = kq * 1536;
  const u16* Ab = connB + (size_t)s * 3145728 + (size_t)row0 * 6144 + k0;
  const u16* Bb = yT + (size_t)s * 393216 + k0;
  __shared__ __align__(16) u16 lds[3 * 2 * 4096];  // 48 KB: [buf][A|B][64*64]
  const int tid = threadIdx.x, lane = tid & 63, wid = tid >> 6;
  const int r = lane & 15, g = lane >> 4;
  const int wr = wid & 3, wc = wid >> 2;
  const int isA = wid < 4;
  const int wseg = (isA ? wid : wid - 4) * 16;
  const u16* sbase = isA ? Ab : Bb;
  const int lrow = lane >> 3, lslot = lane & 7;
  const int side = isA ? 0 : 1;
  f32x4 acc[2] = {};

#define STAGE(T, NB)                                                            \
  {                                                                             \
    u16* dst = &lds[((NB) * 2 + side) * 4096];                                  \
    _Pragma("unroll")                                                           \
    for (int h = 0; h < 2; ++h) {                                               \
      const int R0 = wseg + h * 8;                                              \
      const int row = R0 + lrow;                                                \
      const int slot = lslot ^ (row & 7);                                       \
      gload16(sbase + (size_t)row * 6144 + (size_t)(T) * 64 + slot * 8,         \
              dst + R0 * 64);                                                   \
    }                                                                           \
  }

  STAGE(0, 0);
  STAGE(1, 1);
  int nb = 0;
  for (int t = 0; t < 24; ++t) {
    if (t < 23) { asm volatile("s_waitcnt vmcnt(2)" ::: "memory"); }
    else        { asm volatile("s_waitcnt vmcnt(0)" ::: "memory"); }
    __builtin_amdgcn_s_barrier();
    if (t + 2 < 24) {
      int nb2 = nb + 2; if (nb2 >= 3) nb2 -= 3;
      STAGE(t + 2, nb2);
    }
    {
      const u16* bufA = &lds[(nb * 2 + 0) * 4096];
      const u16* bufB = &lds[(nb * 2 + 1) * 4096];
      const int arow = wr * 16 + r;
#pragma unroll
      for (int ks = 0; ks < 2; ++ks) {
        bf16x8 av = *(const bf16x8*)&bufA[arow * 64 + ((((ks << 2) + g) ^ (arow & 7)) << 3)];
#pragma unroll
        for (int c = 0; c < 2; ++c) {
          const int col = wc * 32 + c * 16 + r;
          bf16x8 bv = *(const bf16x8*)&bufB[col * 64 + ((((ks << 2) + g) ^ (col & 7)) << 3)];
          acc[c] = __builtin_amdgcn_mfma_f32_16x16x32_bf16(av, bv, acc[c], 0, 0, 0);
        }
      }
    }
    if (++nb >= 3) nb -= 3;
  }
#undef STAGE
  float* po = pOut + (size_t)kq * 524288 + ((size_t)s * 512 + row0) * 64;
#pragma unroll
  for (int c = 0; c < 2; ++c)
#pragma unroll
    for (int r2 = 0; r2 < 4; ++r2) {
      int m = wr * 16 + g * 4 + r2;
      int o = wc * 32 + c * 16 + r;
      po[m * 64 + o] = acc[c][r2];
    }
}

// ---------- fallback (f32, correct, slow) if ws too small ----------
__global__ __launch_bounds__(256) void k_fb_conv(const float* __restrict__ x,
                                                 const float* __restrict__ conn,
                                                 const float* __restrict__ bond,
                                                 const float* __restrict__ filt,
                                                 const float* __restrict__ node,
                                                 float* __restrict__ out, int addNode) {
  const int s = blockIdx.y, a = blockIdx.x;
  const int t = threadIdx.x;
  const int f = t & 63, lg = t >> 6;
  __shared__ float ncv[12 * 64];
  __shared__ float red[4][64];
  const float* cb = conn + ((size_t)(s * 512 + a)) * 6144;
  const float* xb = x + (size_t)s * 32768;
  float a0 = 0.f, a1 = 0.f, a2 = 0.f;
  for (int k = 0; k < 512; ++k) {
    float xv = xb[k * 64 + f];
    const float* cr = cb + k * 12 + lg * 3;
    a0 += cr[0] * xv; a1 += cr[1] * xv; a2 += cr[2] * xv;
  }
  ncv[(lg * 3 + 0) * 64 + f] = a0;
  ncv[(lg * 3 + 1) * 64 + f] = a1;
  ncv[(lg * 3 + 2) * 64 + f] = a2;
  __syncthreads();
  float p = 0.f;
  for (int l = lg * 3; l < lg * 3 + 3; ++l) {
    const float* wr = filt + ((size_t)(f * 12 + l)) * 66;
    float q = 0.f;
    for (int f2 = 0; f2 < 64; ++f2) q += ncv[l * 64 + f2] * wr[f2];
    q += bond[((size_t)(s * 512 + a) * 12 + l) * 2 + 0] * wr[64];
    q += bond[((size_t)(s * 512 + a) * 12 + l) * 2 + 1] * wr[65];
    p += q;
  }
  red[lg][f] = p;
  __syncthreads();
  if (t < 64) {
    float v = red[0][t] + red[1][t] + red[2][t] + red[3][t];
    if (addNode) v += node[((size_t)(s * 512 + a)) * 64 + t];
    out[((size_t)(s * 512 + a)) * 64 + t] = fmaxf(v, 0.f);
  }
}

extern "C" void kernel_launch(void* const* d_in, const int* in_sizes, int n_in,
                              void* d_out, int out_size, void* d_ws, size_t ws_size,
                              hipStream_t stream) {
  (void)in_sizes; (void)n_in; (void)out_size;
  const float* node    = (const float*)d_in[0];
  const float* conn    = (const float*)d_in[1];
  const float* bond    = (const float*)d_in[2];
  const float* filters = (const float*)d_in[3];
  float* outF = (float*)d_out;

  const size_t OFF_CONNB = 0;           // 16*512*6144*2 = 100,663,296
  const size_t OFF_YT    = 100663296;   // 16*64*6144*2  =  12,582,912
  const size_t OFF_WA    = 113246208;   // 3*768*64*2    =     294,912
  const size_t OFF_BW    = 113541120;   // 3*16*512*64*4 =   6,291,456
  const size_t OFF_POUT  = 119832576;   // 4*16*512*64*4 =   8,388,608
  const size_t WS_NEED   = 128221184;

  if (ws_size >= WS_NEED) {
    unsigned char* ws = (unsigned char*)d_ws;
    u16* connB = (u16*)(ws + OFF_CONNB);
    u16* yT    = (u16*)(ws + OFF_YT);
    u16* wA    = (u16*)(ws + OFF_WA);
    float* bW  = (float*)(ws + OFF_BW);
    float* pO  = (float*)(ws + OFF_POUT);

    k_prep<<<dim3(3136), dim3(256), 0, stream>>>(conn, filters, bond, connB, wA, bW);
    k_yT<<<dim3(128), dim3(512), 0, stream>>>(node, pO, bW, wA, yT, outF, 0, 0);
    for (int j = 0; j < 6; ++j) {
      k_stageB<<<dim3(512), dim3(512), 0, stream>>>(connB, yT, pO);
      if (j < 5) {
        k_yT<<<dim3(128), dim3(512), 0, stream>>>(node, pO,
                                                  bW + (size_t)(j >> 1) * 524288,
                                                  wA + (size_t)((j + 1) >> 1) * 49152,
                                                  yT, outF, 1, j & 1);
      } else {
        k_yT<<<dim3(128), dim3(512), 0, stream>>>(node, pO, bW + (size_t)2 * 524288,
                                                  wA, yT, outF, 2, 1);
      }
    }
  } else {
    float* buf = (float*)d_ws;
    const float* xc = node;
    for (int j = 0; j < 6; ++j) {
      int i = j >> 1;
      float* dst = (j & 1) ? outF : buf;
      k_fb_conv<<<dim3(512, 16), dim3(256), 0, stream>>>(xc, conn, bond,
                                                         filters + (size_t)i * 50688,
                                                         node, dst, j & 1);
      xc = dst;
    }
  }
}